// Round 6
// baseline (150.725 us; speedup 1.0000x reference)
//
#include <hip/hip_runtime.h>
#include <hip/hip_bf16.h>

// MSEL_Feat: fused per-identity loss, single pass, FORCED-MLP loads.
//   N=8192, D=2048, num_pos=4, id_num=2048.
//   Per identity, everything derives from 25 scalars:
//     rr[p]=|r_p|^2, ii[p]=|ir_p|^2, sr[p]=S.r_p, si[p]=S.ir_p,
//     ri[p]=r_p.ir_p, rt[p]=r_p.T, tt=|T|^2   (S=sum_p r_p, T=sum_p ir_p)
//
// R2/R3/R5 all pinned at ~46-52 us, 1.4 TB/s HBM, VGPR<=48: the compiler
// serializes the staging loads (2-4 in flight) -> latency-bound. This round
// forces 16 outstanding global_load_dwordx4 per thread via inline asm
// (SGPR base + 32b voffset), one s_waitcnt vmcnt(0) that owns all 16
// results as "+v" operands (consumers depend on the waitcnt, rule #18),
// then sched_barrier(0). VGPR_Count >= 96 is the verification knob.

typedef float f32x4 __attribute__((ext_vector_type(4)));

constexpr int D    = 2048;
constexpr int NPOS = 4;
constexpr int TPB  = 256;
constexpr int NACC = 25;

__global__ void zero_out_kernel(float* out) { out[0] = 0.0f; }

__global__ void __launch_bounds__(TPB, 2) msel_feat_kernel(
        const float* __restrict__ in1,   // RGB feats [N, D]
        const float* __restrict__ in2,   // IR  feats [N, D]
        float* __restrict__ out) {
    const long id = blockIdx.x;
    const float* __restrict__ ra = in1 + id * (long)(NPOS * D);
    const float* __restrict__ rb = in2 + id * (long)(NPOS * D);

    // byte offsets within the identity's 32KB block: row p (8KB) + half h (4KB) + lane
    unsigned ofs[8];
#pragma unroll
    for (int p = 0; p < NPOS; ++p) {
#pragma unroll
        for (int h = 0; h < 2; ++h)
            ofs[p * 2 + h] = (unsigned)(p * (D * 4) + h * 4096 + threadIdx.x * 16);
    }

    // ---- 32 forced-in-flight loads per wavefront pair: 16 per thread ----
    f32x4 a0, a1, a2, a3, a4, a5, a6, a7;   // in1: idx = p*2+h
    f32x4 b0, b1, b2, b3, b4, b5, b6, b7;   // in2: idx = p*2+h
#define MSEL_LD(dst, off, base) \
    asm volatile("global_load_dwordx4 %0, %1, %2" : "=v"(dst) : "v"(off), "s"(base))
    MSEL_LD(a0, ofs[0], ra); MSEL_LD(a1, ofs[1], ra);
    MSEL_LD(a2, ofs[2], ra); MSEL_LD(a3, ofs[3], ra);
    MSEL_LD(a4, ofs[4], ra); MSEL_LD(a5, ofs[5], ra);
    MSEL_LD(a6, ofs[6], ra); MSEL_LD(a7, ofs[7], ra);
    MSEL_LD(b0, ofs[0], rb); MSEL_LD(b1, ofs[1], rb);
    MSEL_LD(b2, ofs[2], rb); MSEL_LD(b3, ofs[3], rb);
    MSEL_LD(b4, ofs[4], rb); MSEL_LD(b5, ofs[5], rb);
    MSEL_LD(b6, ofs[6], rb); MSEL_LD(b7, ofs[7], rb);
#undef MSEL_LD

    // single drain; all 16 results flow THROUGH this asm (data dep, rule #18)
    asm volatile("s_waitcnt vmcnt(0)"
                 : "+v"(a0), "+v"(a1), "+v"(a2), "+v"(a3),
                   "+v"(a4), "+v"(a5), "+v"(a6), "+v"(a7),
                   "+v"(b0), "+v"(b1), "+v"(b2), "+v"(b3),
                   "+v"(b4), "+v"(b5), "+v"(b6), "+v"(b7));
    __builtin_amdgcn_sched_barrier(0);

    const f32x4 rA[2][NPOS] = {{a0, a2, a4, a6}, {a1, a3, a5, a7}};
    const f32x4 iA[2][NPOS] = {{b0, b2, b4, b6}, {b1, b3, b5, b7}};

    float acc[NACC];
#pragma unroll
    for (int k = 0; k < NACC; ++k) acc[k] = 0.0f;

#pragma unroll
    for (int h = 0; h < 2; ++h) {
#pragma unroll
        for (int e = 0; e < 4; ++e) {
            const float x0 = rA[h][0][e], x1 = rA[h][1][e],
                        x2 = rA[h][2][e], x3 = rA[h][3][e];
            const float y0 = iA[h][0][e], y1 = iA[h][1][e],
                        y2 = iA[h][2][e], y3 = iA[h][3][e];
            const float s = x0 + x1 + x2 + x3;
            const float t = y0 + y1 + y2 + y3;
            const float x[NPOS] = {x0, x1, x2, x3};
            const float y[NPOS] = {y0, y1, y2, y3};
            acc[24] = fmaf(t, t, acc[24]);                    // |T|^2
#pragma unroll
            for (int p = 0; p < NPOS; ++p) {
                acc[0  + p] = fmaf(x[p], x[p], acc[0  + p]);  // rr
                acc[4  + p] = fmaf(y[p], y[p], acc[4  + p]);  // ii
                acc[8  + p] = fmaf(s,    x[p], acc[8  + p]);  // sr
                acc[12 + p] = fmaf(s,    y[p], acc[12 + p]);  // si
                acc[16 + p] = fmaf(x[p], y[p], acc[16 + p]);  // ri
                acc[20 + p] = fmaf(x[p], t,    acc[20 + p]);  // rt
            }
        }
    }

    // ---- 64-lane wave reduce each accumulator ----
#pragma unroll
    for (int k = 0; k < NACC; ++k) {
        float v = acc[k];
#pragma unroll
        for (int off = 32; off > 0; off >>= 1) v += __shfl_down(v, off, 64);
        acc[k] = v;
    }

    __shared__ float lds[TPB / 64][NACC];
    const int wave = threadIdx.x >> 6;
    const int lane = threadIdx.x & 63;
    if (lane == 0) {
#pragma unroll
        for (int k = 0; k < NACC; ++k) lds[wave][k] = acc[k];
    }
    __syncthreads();

    if (threadIdx.x == 0) {
        float tot[NACC];
#pragma unroll
        for (int k = 0; k < NACC; ++k)
            tot[k] = lds[0][k] + lds[1][k] + lds[2][k] + lds[3][k];

        const float ss = tot[8] + tot[9] + tot[10] + tot[11];  // |S|^2
        const float tt = tot[24];                              // |T|^2
        float contrib = 0.0f;
#pragma unroll
        for (int p = 0; p < NPOS; ++p) {
            const float rr = tot[0 + p];
            const float ii = tot[4 + p];
            const float sr = tot[8 + p];
            const float si = tot[12 + p];
            const float ri = tot[16 + p];
            const float rt = tot[20 + p];

            // |loo_p|^2 = (|S|^2 - 2 S.r_p + |r_p|^2)/9
            const float b2loo = (ss - 2.0f * sr + rr) * (1.0f / 9.0f);
            const float sq_intra_rgb = rr + b2loo - 2.0f * ((sr - rr) * (1.0f / 3.0f));
            const float sq_intra_ir  = ii + b2loo - 2.0f * ((si - ri) * (1.0f / 3.0f));
            const float sq_cross_rgb = rr + tt * 0.0625f - 0.5f * rt;
            const float sq_cross_ir  = ii + ss * 0.0625f - 0.5f * si;

            const float d_ir_rgb = sqrtf(fmaxf(sq_intra_rgb, 1e-12f));
            const float d_ir_ir  = sqrtf(fmaxf(sq_intra_ir,  1e-12f));
            const float d_cr_rgb = sqrtf(fmaxf(sq_cross_rgb, 1e-12f));
            const float d_cr_ir  = sqrtf(fmaxf(sq_cross_ir,  1e-12f));

            const float e1 = d_cr_rgb - d_ir_rgb;
            const float e2 = d_cr_ir  - d_ir_ir;
            contrib += e1 * e1 + e2 * e2;
        }
        // loss = sum / N / 2, N = 8192
        atomicAdd(out, contrib * (1.0f / 16384.0f));
    }
}

extern "C" void kernel_launch(void* const* d_in, const int* in_sizes, int n_in,
                              void* d_out, int out_size, void* d_ws, size_t ws_size,
                              hipStream_t stream) {
    const float* in1 = (const float*)d_in[0];
    const float* in2 = (const float*)d_in[1];
    float* out = (float*)d_out;

    const int id_num = in_sizes[0] / (NPOS * D);   // 2048

    zero_out_kernel<<<1, 1, 0, stream>>>(out);
    msel_feat_kernel<<<id_num, TPB, 0, stream>>>(in1, in2, out);
}